// Round 9
// baseline (26038.730 us; speedup 1.0000x reference)
//
#include <hip/hip_runtime.h>
#include <hip/hip_bf16.h>

typedef unsigned short u16;
typedef unsigned int   u32;
typedef unsigned long long u64;

typedef __attribute__((ext_vector_type(8))) short bf16x8;  // 8 x bf16 (4 VGPR) MFMA A/B frag
typedef __attribute__((ext_vector_type(4))) float f32x4;   // MFMA C/D frag
typedef __attribute__((ext_vector_type(4))) u32   u32x4;

#define L2E 1.44269504088896340736f

__device__ __forceinline__ float bf2f(u16 u){ union{u32 i; float f;} v; v.i=((u32)u)<<16; return v.f; }
__device__ __forceinline__ u16  f2bf(float f){ union{float f; u32 i;} v; v.f=f; u32 u=v.i; return (u16)((u + 0x7fffu + ((u>>16)&1u))>>16); }
__device__ __forceinline__ u32  packbf(float a,float b){ return (u32)f2bf(a) | ((u32)f2bf(b)<<16); }
__device__ __forceinline__ float tanh_f(float x){
  float cx = fminf(fmaxf(x,-15.f),15.f);
  float e  = __builtin_amdgcn_exp2f(cx*(2.f*L2E));
  return (e-1.f)*__builtin_amdgcn_rcpf(e+1.f);
}
__device__ __forceinline__ float sig_f(float x){
  float cx = fminf(fmaxf(x,-30.f),30.f);
  float e  = __builtin_amdgcn_exp2f(-cx*L2E);
  return __builtin_amdgcn_rcpf(1.f+e);
}
// Cross-XCD coherent accesses: relaxed agent-scope atomics (bypass per-XCD caches; L3 = coherence point).
__device__ __forceinline__ u64   lda2(const u64* p){ return __hip_atomic_load((u64*)p, __ATOMIC_RELAXED, __HIP_MEMORY_SCOPE_AGENT); }
__device__ __forceinline__ u32   lda1(const u32* p){ return __hip_atomic_load((u32*)p, __ATOMIC_RELAXED, __HIP_MEMORY_SCOPE_AGENT); }
__device__ __forceinline__ void  sta(u32* p, u32 v){ __hip_atomic_store(p, v, __ATOMIC_RELAXED, __HIP_MEMORY_SCOPE_AGENT); }
__device__ __forceinline__ bf16x8 as_bf8(u32x4 w){ union{u32x4 u; bf16x8 b;} c; c.u=w; return c.b; }
// fragment-major address for an h/att element pair: batch r, u32-col c (h element pair 2c,2c+1)
__device__ __forceinline__ int frag_a(int r, int c){
  return ((c>>4)*2 + (r>>4))*256 + (((c>>2)&3))*64 + ((r&15))*4 + (c&3);
}

// ---- batched 32KB L3->LDS stage: 16 independent agent-scope u64 loads in flight, then 16 ds_write_b64 ----
__device__ __forceinline__ void stage32i(u32* lds, const u32* gsrc, int t){
  const u64* g = (const u64*)gsrc;
  u64* d = (u64*)lds;
  u64 r[16];
  #pragma unroll
  for (int k=0;k<16;k++) r[k] = lda2(&g[k*256 + t]);
  #pragma unroll
  for (int k=0;k<16;k++) d[k*256 + t] = r[k];
}

// ---------------- prep: W_ih/W_hh (f32) -> fragment-major bf16 Wf [gs][nt<4][ks<32][lane][8] ----------------
__global__ void k_prep_w(const float* __restrict__ W_ih, const float* __restrict__ W_hh, u16* __restrict__ Wf){
  int idx = blockIdx.x*256 + threadIdx.x;        // 2,097,152
  int j    = idx & 7;
  int lane = (idx >> 3) & 63;
  int ks   = (idx >> 9) & 31;
  int nt   = (idx >> 14) & 3;
  int gs   = idx >> 16;                          // < 32
  int grow = nt*512 + gs*16 + (lane & 15);       // global gate row (nt = gate i/f/g/o)
  int k    = ks*32 + ((lane >> 4) & 3)*8 + j;    // 0..1023: [att 512 | h 512]
  float v = (k < 512) ? W_ih[grow*517 + k] : W_hh[grow*512 + (k - 512)];
  Wf[idx] = f2bf(v);
}
// ---------------- prep: K_conv (f32) -> fragment-major bf16 Kf [tap][nt<16][ks<16][lane][8] ----------------
__global__ void k_prep_kf(const float* __restrict__ Kc, u16* __restrict__ Kf){
  int idx = blockIdx.x*256 + threadIdx.x;        // 1,179,648
  int j    = idx & 7;
  int lane = (idx >> 3) & 63;
  int ks   = (idx >> 9) & 15;
  int nt   = (idx >> 13) & 15;
  int tap  = idx >> 17;                          // < 9
  int oc = nt*16 + (lane & 15);
  int ic = ks*32 + ((lane >> 4) & 3)*8 + j;
  Kf[idx] = f2bf(Kc[(oc*512 + ic)*9 + tap]);
}
// ---------------- prep: W_conv_h (f32) -> FULL fragment-major bf16 WcF2 [nt<16][ks<16][lane][8] ----------------
__global__ void k_prep_wcf2(const float* __restrict__ Wch, u16* __restrict__ WcF2){
  int idx = blockIdx.x*256 + threadIdx.x;        // 131,072
  int j = idx & 7, lane = (idx>>3) & 63, ks = (idx>>9) & 15, nt = idx >> 13;   // nt<16
  int e = nt*16 + (lane & 15);
  int k = ks*32 + ((lane >> 4) & 3)*8 + j;
  WcF2[idx] = f2bf(Wch[e*512 + k]);
}
// ---------------- prep: W_fc_params (f32) -> fragment-major bf16 WpF [ntile<8][ks<16][lane][8] ----------------
__global__ void k_prep_wp(const float* __restrict__ Wp, u16* __restrict__ WpF){
  int idx = blockIdx.x*256 + threadIdx.x;        // 65,536
  int j = idx & 7, lane = (idx>>3) & 63, ks = (idx>>9) & 15, ntile = idx >> 13;
  int n = ntile*16 + (lane & 15);
  int k = ks*32 + (lane >> 4)*8 + j;
  WpF[idx] = (n < 123) ? f2bf(Wp[n*512 + k]) : (u16)0;
}
// ---------------- init: hc = tanh(z @ W_fc_hc^T + b) -> h_pack (fragment-major bf16 pairs), c_ws (f32) ----------------
__global__ void k_hc(const float* __restrict__ z, const float* __restrict__ Wfc, const float* __restrict__ bfc,
                     u32* __restrict__ h_pack, float* __restrict__ c_ws){
  __shared__ float zl[128];
  int b = blockIdx.x, t = threadIdx.x;
  if (t < 128) zl[t] = z[b*128 + t];
  __syncthreads();
  float acc[4];
  #pragma unroll
  for (int i=0;i<4;i++){
    int n = 4*t + i;
    const float* row = Wfc + n*128;
    float a = 0.f;
    #pragma unroll 8
    for (int k2=0;k2<128;k2++) a += row[k2]*zl[k2];
    acc[i] = tanh_f(a + bfc[n]);
  }
  int bg = b >> 5, r = b & 31;
  if (t < 128){
    h_pack[bg*8192 + frag_a(r, 2*t)]   = packbf(acc[0], acc[1]);
    h_pack[bg*8192 + frag_a(r, 2*t+1)] = packbf(acc[2], acc[3]);
  } else {
    int base = 4*t - 512;
    #pragma unroll
    for (int i=0;i<4;i++) c_ws[b*512 + base + i] = acc[i];
  }
}
// ---------------- conv 3x3 SAME (f32 in, bf16 out) + bf16 backbone copy ----------------
__device__ __forceinline__ int xt_addr(int p, int chunk){ return p*512 + ((chunk ^ (p & 7))<<3); } // XOR-swizzled LDS
__global__ __launch_bounds__(256) void k_conv(const float* __restrict__ bb, const u16* __restrict__ Kf,
                       const float* __restrict__ bcf, u16* __restrict__ x_em, u16* __restrict__ bb_bf){
  __shared__ u16 xt[64*512];  // exactly 64KB, swizzled [p][ic]
  int b = blockIdx.x, t = threadIdx.x;
  const float* src = bb + (size_t)b*512*64;
  u16* dstc = bb_bf + (size_t)b*512*64;
  for (int i=0;i<128;i++){
    int idx = i*256 + t;
    int ic = idx >> 6, p = idx & 63;
    u16 v = f2bf(src[idx]);
    xt[xt_addr(p, ic>>3) + (ic&7)] = v;
    dstc[idx] = v;                         // bf16 copy, same [b][c][p] layout
  }
  __syncthreads();
  int wv = t >> 6, l = t & 63, c0 = l & 15, q = l >> 4;
  f32x4 acc[4][4];
  #pragma unroll
  for (int a=0;a<4;a++)
    #pragma unroll
    for (int bq=0;bq<4;bq++) acc[a][bq] = (f32x4)0.f;
  for (int tap=0; tap<9; ++tap){
    int ty = tap/3 - 1, tx = tap%3 - 1;
    for (int ks=0; ks<16; ++ks){
      bf16x8 afr[4];
      #pragma unroll
      for (int mt=0; mt<4; ++mt){
        int p = mt*16 + c0;
        int py = (p >> 3) + ty, px = (p & 7) + tx;
        if ((unsigned)py < 8u && (unsigned)px < 8u){
          afr[mt] = *(const bf16x8*)(&xt[xt_addr(py*8+px, ks*4 + q)]);
        } else {
          afr[mt] = (bf16x8)0;
        }
      }
      #pragma unroll
      for (int ni=0; ni<4; ++ni){
        int nt = wv*4 + ni;
        bf16x8 bfr = as_bf8(*(const u32x4*)(const void*)(Kf + (size_t)((((tap*16 + nt)*16 + ks)*64) + l)*8));
        #pragma unroll
        for (int mt=0; mt<4; ++mt)
          acc[mt][ni] = __builtin_amdgcn_mfma_f32_16x16x32_bf16(afr[mt], bfr, acc[mt][ni], 0,0,0);
      }
    }
  }
  #pragma unroll
  for (int ni=0; ni<4; ++ni){
    int e = (wv*4+ni)*16 + c0;
    float bias = bcf[e];
    #pragma unroll
    for (int mt=0; mt<4; ++mt)
      #pragma unroll
      for (int r=0;r<4;r++){
        int p = mt*16 + q*4 + r;
        x_em[(size_t)(b*256 + e)*64 + p] = f2bf(acc[mt][ni][r] + bias);
      }
  }
}

// ---------------- flag-array barrier (R6-proven): 32 plain relaxed stores to distinct 4B slots;
// wave-0 coalesced ballot poll; __syncthreads release. Data ordering: the arrive-side __syncthreads
// drains vmcnt(0) so all agent-scope data stores are at the coherence point before the flag store. ----
__device__ __forceinline__ void bar_wait(u32* flags, int bg, int t, u32 seq){
  if (t < 32){
    const u32* f = &flags[bg*64 + t];
    for (;;){
      u32 v = lda1(f);
      if (__ballot(v < seq) == 0ull) break;
      __builtin_amdgcn_s_sleep(4);
    }
  }
  __atomic_signal_fence(__ATOMIC_ACQUIRE);   // compiler barrier: data loads stay after the spin
  __syncthreads();                            // release non-polling waves
}

// ---------------- head postprocess, parallelized over all 256 threads ----------------
__device__ __forceinline__ void head_post_par(const float* yL, const float* __restrict__ bp,
                                              float* __restrict__ out, float* mrsL,
                                              int gs, int bg, int t, int step){
  const int CH = 1315840;          // 65792*20
  const int PEN = 7895040;         // 6*CH
  if (gs == 0 && t < 32){
    float m = -1e30f;
    #pragma unroll 1
    for (int c=3;c<23;c++){ float v = yL[t*33 + c] + bp[c]; m = fmaxf(m, v); }
    float su = 0.f;
    #pragma unroll 1
    for (int c=3;c<23;c++){ float v = yL[t*33 + c] + bp[c]; su += __builtin_amdgcn_exp2f((v-m)*L2E); }
    mrsL[t*2]   = m;
    mrsL[t*2+1] = __builtin_amdgcn_rcpf(su);
  }
  __syncthreads();
  int b = t >> 3, cb = (t & 7)*4;
  float m = mrsL[b*2], rs = mrsL[b*2+1];
  int rr = (bg*32 + b)*257 + step;
  #pragma unroll
  for (int i=0;i<4;i++){
    int c2 = cb + i;
    int col = gs*32 + c2;
    if (col >= 123) break;
    float v = yL[b*33 + c2] + bp[col];
    float tv; int oidx;
    if (col < 3){ tv = v; oidx = PEN + rr*3 + col; }
    else {
      int j = col - 3, ch = j/20, jj = j - ch*20;
      if (ch == 0)      tv = __builtin_amdgcn_exp2f((v-m)*L2E)*rs;
      else if (ch <= 2) tv = v;
      else if (ch <= 4) tv = __builtin_amdgcn_exp2f(v*L2E);
      else              tv = tanh_f(v);
      oidx = ch*CH + rr*20 + jj;
    }
    __builtin_nontemporal_store(tv, &out[oidx]);
  }
}
// head C for one bg: MFMA y = h @ Wp^T then postprocess (gs<4 blocks only; gs uniform per block)
__device__ __forceinline__ void head_c(const u32* hF, const u16* __restrict__ WpF,
                                       const float* __restrict__ bp, float* __restrict__ outp,
                                       float* yL, float* mrsL, int gs, int bg, int t, int step){
  int lane = t & 63, wv = t >> 6, c0 = lane & 15, q = lane >> 4;
  int mh = wv & 1, nt2 = wv >> 1;
  f32x4 ya = (f32x4)0.f;
  #pragma unroll 8
  for (int ks=0; ks<16; ++ks){
    bf16x8 bw = as_bf8(*(const u32x4*)(const void*)(WpF + (size_t)((((gs*2+nt2)*16 + ks)*64) + lane)*8));
    bf16x8 ah = *(const bf16x8*)(&hF[(ks*2 + mh)*256 + lane*4]);
    ya = __builtin_amdgcn_mfma_f32_16x16x32_bf16(ah, bw, ya, 0,0,0);
  }
  #pragma unroll
  for (int r=0;r<4;r++) yL[(mh*16 + q*4 + r)*33 + nt2*16 + c0] = ya[r];
  __syncthreads();
  head_post_par(yL, bp, outp, mrsL, gs, bg, t, step);
}

// ---------------- persistent RNN scan + fused head: OFFSET-PIPELINED bg pairs.
// 128 blocks x 256 threads; block handles bg0=2p and bg1=2p+1 in 4 sub-phases per step:
// A0(k), A1(k), B0(k), B1(k) — each with its own flag wait/arrive (seq per bg: A sets 2k+1,
// B sets 2k+2). att0's publish->consume gap is filled by A1's compute; h0's gap by B1's:
// barrier propagation latency overlaps the sibling domain's compute instead of being exposed.
// The single-seq chain also orders the h_pack/att_pack WAR: a publisher can only pass its wait
// after every block flag-acknowledged the reads of the value about to be overwritten. ----------------
__global__ __launch_bounds__(256, 1) void k_rnn(
    const u16* __restrict__ bb_bf, const float* __restrict__ sketch,
    const float* __restrict__ b_ch, const float* __restrict__ Watt,
    const float* __restrict__ W_ih, const float* __restrict__ b_ih, const float* __restrict__ b_hh,
    const u16* __restrict__ x_em, const u16* __restrict__ Wf, const u16* __restrict__ WcF2,
    const u16* __restrict__ WpF, const float* __restrict__ bp,
    u32* __restrict__ h_pack, u32* __restrict__ att_pack,
    const float* __restrict__ c_ws, u32* __restrict__ flags, float* __restrict__ outp)
{
  __shared__ __align__(16) u32 hA0[8192];     // 32KB: bg0 h fragments, reused for att in B0
  __shared__ __align__(16) u32 hA1[8192];     // 32KB: bg1
  __shared__ __align__(16) u16 x_emL0[16384]; // 32KB: x_em[ba0], staged once (L2-thrash fix vs R8)
  __shared__ __align__(16) u16 x_emL1[16384]; // 32KB: x_em[ba1]
  __shared__ __align__(16) u32 xaH[2112];     // 8.4KB: stgL (scores) / gbufL (gates), phase-aliased
  __shared__ float gemA[256];     // g_em row for current phase's batch (bias folded)
  __shared__ float wattA[256];
  __shared__ float bchA[256];
  __shared__ float alphaL[64];
  __shared__ float ptL0[256], ptL1[256];
  __shared__ float w5L[512];
  __shared__ float biasL[64];
  __shared__ float yL[1056];
  __shared__ float mrsL[64];
  float* gbufL = (float*)xaH;
  float* stgL  = (float*)xaH;

  int t = threadIdx.x;
  int pr = blockIdx.x >> 5, gs = blockIdx.x & 31;
  int bg0 = pr*2, bg1 = bg0 + 1;
  int lane = t & 63, wv = t >> 6;
  int c0 = lane & 15, q = lane >> 4;

  // one-time staging (gs-indexed -> shared by both bgs)
  wattA[t] = Watt[t];
  bchA[t]  = b_ch[t];
  if (t < 64){
    int grow = (t >> 4)*512 + gs*16 + (t & 15);
    biasL[t] = b_ih[grow] + b_hh[grow];
    #pragma unroll
    for (int d=0; d<5; ++d) w5L[t*8+d] = W_ih[grow*517 + 512 + d];
  }
  int bL = t & 31, hp = t >> 5;              // LSTM role
  float c00 = c_ws[(bg0*32 + bL)*512 + gs*16 + 2*hp];
  float c01 = c_ws[(bg0*32 + bL)*512 + gs*16 + 2*hp + 1];
  float c10 = c_ws[(bg1*32 + bL)*512 + gs*16 + 2*hp];
  float c11 = c_ws[(bg1*32 + bL)*512 + gs*16 + 2*hp + 1];
  int ba0 = bg0*32 + gs, ba1 = bg1*32 + gs;  // own batches
  int mh_g = gs >> 4;
  int rq = (gs & 15) >> 2, rj = gs & 3;
  const u16* wb  = Wf   + (size_t)(((gs*4 + wv)*32)*64 + lane)*8;
  const u16* wcb = WcF2 + (size_t)((wv*4)*16*64 + lane)*8;
  const u32* hsrc0 = h_pack + (size_t)bg0*8192;
  const u32* hsrc1 = h_pack + (size_t)bg1*8192;
  const u32* asrc0 = att_pack + (size_t)bg0*8192;
  const u32* asrc1 = att_pack + (size_t)bg1*8192;
  int hpub_a = frag_a(bL, gs*8 + hp);
  int apub_a = ((gs>>4)<<12) + ((t>>4)<<8) + (((t>>2)&3)<<6) + ((gs&15)<<2) + (t&3);
  u32* hpub0 = h_pack + (size_t)bg0*8192 + hpub_a;
  u32* hpub1 = h_pack + (size_t)bg1*8192 + hpub_a;
  u32* apub0 = att_pack + (size_t)bg0*8192 + apub_a;
  u32* apub1 = att_pack + (size_t)bg1*8192 + apub_a;
  // step-invariant gate weights in registers (shared by both bgs)
  bf16x8 wfA[16], wfH[16];
  #pragma unroll
  for (int k=0;k<16;k++){
    wfA[k] = as_bf8(*(const u32x4*)(const void*)(wb + (size_t)k*512));
    wfH[k] = as_bf8(*(const u32x4*)(const void*)(wb + (size_t)(16+k)*512));
  }
  // stage both x_em slices (32KB each = 2048 u32x4 = 8/thread — bounds verified, R3/R4 lesson)
  {
    const u32x4* xs0 = (const u32x4*)(x_em + (size_t)ba0*16384);
    const u32x4* xs1 = (const u32x4*)(x_em + (size_t)ba1*16384);
    u32x4* xd0 = (u32x4*)x_emL0;
    u32x4* xd1 = (u32x4*)x_emL1;
    #pragma unroll
    for (int i=0;i<8;i++){ xd0[i*256 + t] = xs0[i*256 + t]; xd1[i*256 + t] = xs1[i*256 + t]; }
  }
  // pt for ts=0 (start token), both bgs
  if (t < 64){
    float* pl = (t < 32) ? ptL0 : ptL1;
    int r = t & 31;
    pl[r*8+0]=0.f; pl[r*8+1]=0.f; pl[r*8+2]=1.f; pl[r*8+3]=0.f; pl[r*8+4]=0.f;
  }

  // ---- phase bodies ----
  auto do_score = [&](const u16* xL, const float* gem){
    int eg = t >> 3, ps = t & 7;
    float sp[8];
    #pragma unroll
    for (int j=0;j<8;j++) sp[j] = 0.f;
    const u16* xb = xL + (size_t)(eg*8)*64 + ps*8;
    #pragma unroll
    for (int e2=0; e2<8; ++e2){
      float gev = gem[eg*8 + e2];
      float wev = wattA[eg*8 + e2];
      bf16x8 xv = *(const bf16x8*)(xb + (size_t)e2*64);
      #pragma unroll
      for (int j=0;j<8;j++)
        sp[j] += tanh_f(bf2f((u16)xv[j]) + gev) * wev;
    }
    #pragma unroll
    for (int j=0;j<8;j++) stgL[eg*64 + ps*8 + j] = sp[j];
  };
  auto do_softmax = [&](){
    if (t < 64){
      float s = 0.f;
      #pragma unroll
      for (int g2=0; g2<32; ++g2) s += stgL[g2*64 + t];
      float m = s;
      #pragma unroll
      for (int d=1; d<64; d<<=1) m = fmaxf(m, __shfl_xor(m, d, 64));
      float ex = __builtin_amdgcn_exp2f((s - m) * L2E);
      float su = ex;
      #pragma unroll
      for (int d=1; d<64; d<<=1) su += __shfl_xor(su, d, 64);
      alphaL[t] = ex * __builtin_amdgcn_rcpf(su);
    }
  };
  auto do_att = [&](int ba, u32* apub){
    const u16* base = bb_bf + (size_t)(ba*512 + 2*t)*64;
    float a0 = 0.f, a1 = 0.f;
    #pragma unroll
    for (int p8=0; p8<8; ++p8){
      bf16x8 v0 = *(const bf16x8*)(base + p8*8);
      bf16x8 v1 = *(const bf16x8*)(base + 64 + p8*8);
      #pragma unroll
      for (int j=0;j<8;j++){
        float al = alphaL[p8*8+j];
        a0 += al * bf2f((u16)v0[j]);
        a1 += al * bf2f((u16)v1[j]);
      }
    }
    sta(apub, packbf(a0, a1));
  };
  auto do_lstm = [&](const float* pl, float& cA, float& cB, u32* hpub){
    float p0v = pl[bL*8+0], p1v = pl[bL*8+1], p2v = pl[bL*8+2], p3v = pl[bL*8+3], p4v = pl[bL*8+4];
    auto gval = [&](int n)->float {
      return gbufL[n*33 + bL] + biasL[n]
           + p0v*w5L[n*8+0] + p1v*w5L[n*8+1] + p2v*w5L[n*8+2] + p3v*w5L[n*8+3] + p4v*w5L[n*8+4];
    };
    float hv0 = 0.f, hv1 = 0.f;
    #pragma unroll
    for (int k2=0;k2<2;k2++){
      int hh = 2*hp + k2;
      float gi = gval(hh), gf = gval(16+hh), gg = gval(32+hh), go = gval(48+hh);
      float cp = k2 ? cB : cA;
      float cn = sig_f(gf)*cp + sig_f(gi)*tanh_f(gg);
      float hv = sig_f(go)*tanh_f(cn);
      if (k2){ cB = cn; hv1 = hv; } else { cA = cn; hv0 = hv; }
    }
    sta(hpub, packbf(hv0, hv1));
  };
  // A-phase: wait h(k), stage it, g_em + h-half gates (gates held in gA/gB regs), head-C(k-1),
  // scores/softmax/att, publish att(k), flag 2k+1.
  auto phaseA = [&](int bg, int ba, u32* hA, const u16* xL, const u32* hsrc, u32* apub,
                    f32x4& gA, f32x4& gB, int k){
    bar_wait(flags, bg, t, 2u*(u32)k);
    stage32i(hA, hsrc, t);
    __syncthreads();
    {
      f32x4 e0=(f32x4)0.f, e1=(f32x4)0.f, e2=(f32x4)0.f, e3=(f32x4)0.f;
      gA = (f32x4)0.f; gB = (f32x4)0.f;
      #pragma unroll
      for (int ks=0; ks<16; ++ks){
        bf16x8 hk = *(const bf16x8*)(&hA[(ks*2 + mh_g)*256 + lane*4]);
        bf16x8 b0 = as_bf8(*(const u32x4*)(const void*)(wcb + (size_t)(0*16 + ks)*512));
        bf16x8 b1 = as_bf8(*(const u32x4*)(const void*)(wcb + (size_t)(1*16 + ks)*512));
        bf16x8 b2 = as_bf8(*(const u32x4*)(const void*)(wcb + (size_t)(2*16 + ks)*512));
        bf16x8 b3 = as_bf8(*(const u32x4*)(const void*)(wcb + (size_t)(3*16 + ks)*512));
        e0 = __builtin_amdgcn_mfma_f32_16x16x32_bf16(hk, b0, e0, 0,0,0);
        e1 = __builtin_amdgcn_mfma_f32_16x16x32_bf16(hk, b1, e1, 0,0,0);
        e2 = __builtin_amdgcn_mfma_f32_16x16x32_bf16(hk, b2, e2, 0,0,0);
        e3 = __builtin_amdgcn_mfma_f32_16x16x32_bf16(hk, b3, e3, 0,0,0);
        bf16x8 x0 = *(const bf16x8*)(&hA[(ks*2)*256 + lane*4]);
        bf16x8 x1 = *(const bf16x8*)(&hA[(ks*2+1)*256 + lane*4]);
        gA = __builtin_amdgcn_mfma_f32_16x16x32_bf16(x0, wfH[ks], gA, 0,0,0);
        gB = __builtin_amdgcn_mfma_f32_16x16x32_bf16(x1, wfH[ks], gB, 0,0,0);
      }
      if (q == rq){
        gemA[(wv*4+0)*16 + c0] = e0[rj] + bchA[(wv*4+0)*16 + c0];
        gemA[(wv*4+1)*16 + c0] = e1[rj] + bchA[(wv*4+1)*16 + c0];
        gemA[(wv*4+2)*16 + c0] = e2[rj] + bchA[(wv*4+2)*16 + c0];
        gemA[(wv*4+3)*16 + c0] = e3[rj] + bchA[(wv*4+3)*16 + c0];
      }
    }
    __syncthreads();
    if (gs < 4 && k > 0) head_c(hA, WpF, bp, outp, yL, mrsL, gs, bg, t, k-1);
    do_score(xL, gemA);
    __syncthreads();
    do_softmax();
    __syncthreads();
    do_att(ba, apub);
    __syncthreads();               // drain att stores to coherence point
    if (t == 0) sta(&flags[bg*64 + gs], 2u*(u32)k + 1u);
  };
  // B-phase: wait att(k), stage into the (now dead) h slot, att-half gates, LSTM,
  // publish h(k+1), flag 2k+2; pt(k+1) staged in the shadow.
  auto phaseB = [&](int bg, u32* hA, const u32* asrc, float* pl,
                    float& cA, float& cB, u32* hpub, f32x4& gA, f32x4& gB, int k){
    bar_wait(flags, bg, t, 2u*(u32)k + 1u);
    stage32i(hA, asrc, t);
    __syncthreads();
    #pragma unroll
    for (int kc=0; kc<16; ++kc){
      bf16x8 a0 = *(const bf16x8*)(&hA[kc*256 + lane*4]);
      bf16x8 a1 = *(const bf16x8*)(&hA[4096 + kc*256 + lane*4]);
      gA = __builtin_amdgcn_mfma_f32_16x16x32_bf16(a0, wfA[kc], gA, 0,0,0);
      gB = __builtin_amdgcn_mfma_f32_16x16x32_bf16(a1, wfA[kc], gB, 0,0,0);
    }
    {
      int n = wv*16 + c0;
      #pragma unroll
      for (int r=0;r<4;r++){
        gbufL[n*33 + (q*4 + r)]      = gA[r];
        gbufL[n*33 + (16 + q*4 + r)] = gB[r];
      }
    }
    __syncthreads();
    do_lstm(pl, cA, cB, hpub);
    __syncthreads();               // drain h stores to coherence point
    if (t == 0) sta(&flags[bg*64 + gs], 2u*(u32)k + 2u);
    if (k < 256 && t < 32){
      const float* sp2 = sketch + ((size_t)k*256 + bg*32 + t)*5;
      pl[t*8+0]=sp2[0]; pl[t*8+1]=sp2[1]; pl[t*8+2]=sp2[2]; pl[t*8+3]=sp2[3]; pl[t*8+4]=sp2[4];
    }
  };

  f32x4 g00, g01, g10, g11;
  __syncthreads();

  #pragma clang loop unroll(disable)
  for (int k=0; k<257; ++k){
    phaseA(bg0, ba0, hA0, x_emL0, hsrc0, apub0, g00, g01, k);
    phaseA(bg1, ba1, hA1, x_emL1, hsrc1, apub1, g10, g11, k);
    phaseB(bg0, hA0, asrc0, ptL0, c00, c01, hpub0, g00, g01, k);
    phaseB(bg1, hA1, asrc1, ptL1, c10, c11, hpub1, g10, g11, k);
  }
  // ======== epilogue: head for step 256 (h_257 now in h_pack), both bgs ========
  if (gs < 4){
    bar_wait(flags, bg0, t, 514u);
    stage32i(hA0, hsrc0, t);
    __syncthreads();
    head_c(hA0, WpF, bp, outp, yL, mrsL, gs, bg0, t, 256);
    bar_wait(flags, bg1, t, 514u);
    stage32i(hA1, hsrc1, t);
    __syncthreads();
    head_c(hA1, WpF, bp, outp, yL, mrsL, gs, bg1, t, 256);
  }
}

extern "C" void kernel_launch(void* const* d_in, const int* in_sizes, int n_in,
                              void* d_out, int out_size, void* d_ws, size_t ws_size,
                              hipStream_t stream){
  (void)in_sizes; (void)n_in; (void)out_size; (void)ws_size;
  const float* backbone = (const float*)d_in[0];
  const float* z_vec    = (const float*)d_in[1];
  const float* sketch   = (const float*)d_in[2];
  const float* W_fc_hc  = (const float*)d_in[3];
  const float* b_fc_hc  = (const float*)d_in[4];
  const float* W_conv_h = (const float*)d_in[5];
  const float* b_conv_h = (const float*)d_in[6];
  const float* K_conv_f = (const float*)d_in[7];
  const float* b_conv_f = (const float*)d_in[8];
  const float* W_att    = (const float*)d_in[9];
  // d_in[10] = b_conv_att: additive constant to all scores -> softmax-invariant, skipped
  const float* W_ih     = (const float*)d_in[11];
  const float* W_hh     = (const float*)d_in[12];
  const float* b_ih     = (const float*)d_in[13];
  const float* b_hh     = (const float*)d_in[14];
  const float* W_fcp    = (const float*)d_in[15];
  const float* b_fcp    = (const float*)d_in[16];

  char* ws = (char*)d_ws;
  u32*   flags    = (u32*)(ws + 0);              // 16,384 (8 bg x 32 flags, 4B stride)
  u32*   h_pack   = (u32*)(ws + 16384);          // 262,144 (fragment-major per bg)
  u32*   att_pack = (u32*)(ws + 278528);         // 262,144 (fragment-major per bg)
  float* c_ws     = (float*)(ws + 2637824);      // 524,288
  u16*   x_em     = (u16*)(ws + 3162112);        // 8,388,608
  u16*   Wf       = (u16*)(ws + 11550720);       // 4,194,304
  u16*   Kf       = (u16*)(ws + 15745024);       // 2,359,296
  u16*   WcF2     = (u16*)(ws + 18104320);       // 262,144
  u16*   WpF      = (u16*)(ws + 18628608);       // 131,072
  u16*   bb_bf    = (u16*)(ws + 18759680);       // 4,194,304

  (void)hipMemsetAsync(flags, 0, 16384, stream);
  k_prep_w  <<<8192, 256, 0, stream>>>(W_ih, W_hh, Wf);
  k_prep_kf <<<4608, 256, 0, stream>>>(K_conv_f, Kf);
  k_prep_wcf2<<<512, 256, 0, stream>>>(W_conv_h, WcF2);
  k_prep_wp <<<256,  256, 0, stream>>>(W_fcp, WpF);
  k_hc      <<<256,  256, 0, stream>>>(z_vec, W_fc_hc, b_fc_hc, h_pack, c_ws);
  k_conv    <<<256,  256, 0, stream>>>(backbone, Kf, b_conv_f, x_em, bb_bf);
  k_rnn     <<<128,  256, 0, stream>>>(bb_bf, sketch, b_conv_h, W_att, W_ih, b_ih, b_hh,
                                       x_em, Wf, WcF2, WpF, b_fcp,
                                       h_pack, att_pack, c_ws, flags, (float*)d_out);
}

// Round 10
// 10933.085 us; speedup vs baseline: 2.3816x; 2.3816x over previous
//
#include <hip/hip_runtime.h>
#include <hip/hip_bf16.h>

typedef unsigned short u16;
typedef unsigned int   u32;
typedef unsigned long long u64;

typedef __attribute__((ext_vector_type(8))) short bf16x8;  // 8 x bf16 (4 VGPR) MFMA A/B frag
typedef __attribute__((ext_vector_type(4))) float f32x4;   // MFMA C/D frag
typedef __attribute__((ext_vector_type(4))) u32   u32x4;

#define L2E 1.44269504088896340736f

__device__ __forceinline__ float bf2f(u16 u){ union{u32 i; float f;} v; v.i=((u32)u)<<16; return v.f; }
__device__ __forceinline__ u16  f2bf(float f){ union{float f; u32 i;} v; v.f=f; u32 u=v.i; return (u16)((u + 0x7fffu + ((u>>16)&1u))>>16); }
__device__ __forceinline__ u32  packbf(float a,float b){ return (u32)f2bf(a) | ((u32)f2bf(b)<<16); }
__device__ __forceinline__ float tanh_f(float x){
  float cx = fminf(fmaxf(x,-15.f),15.f);
  float e  = __builtin_amdgcn_exp2f(cx*(2.f*L2E));
  return (e-1.f)*__builtin_amdgcn_rcpf(e+1.f);
}
__device__ __forceinline__ float sig_f(float x){
  float cx = fminf(fmaxf(x,-30.f),30.f);
  float e  = __builtin_amdgcn_exp2f(-cx*L2E);
  return __builtin_amdgcn_rcpf(1.f+e);
}
// Cross-XCD coherent accesses: relaxed agent-scope atomics (bypass per-XCD caches; L3 = coherence point).
__device__ __forceinline__ u64   lda2(const u64* p){ return __hip_atomic_load((u64*)p, __ATOMIC_RELAXED, __HIP_MEMORY_SCOPE_AGENT); }
__device__ __forceinline__ u32   lda1(const u32* p){ return __hip_atomic_load((u32*)p, __ATOMIC_RELAXED, __HIP_MEMORY_SCOPE_AGENT); }
__device__ __forceinline__ void  sta(u32* p, u32 v){ __hip_atomic_store(p, v, __ATOMIC_RELAXED, __HIP_MEMORY_SCOPE_AGENT); }
__device__ __forceinline__ bf16x8 as_bf8(u32x4 w){ union{u32x4 u; bf16x8 b;} c; c.u=w; return c.b; }
// fragment-major address for an h/att element pair: batch r, u32-col c (h element pair 2c,2c+1)
__device__ __forceinline__ int frag_a(int r, int c){
  return ((c>>4)*2 + (r>>4))*256 + (((c>>2)&3))*64 + ((r&15))*4 + (c&3);
}

// ---- batched 32KB L3->LDS stage with 512 threads: 8 independent agent-scope u64 loads in flight ----
__device__ __forceinline__ void stage32h(u32* lds, const u32* gsrc, int t){
  const u64* g = (const u64*)gsrc;
  u64* d = (u64*)lds;
  u64 r[8];
  #pragma unroll
  for (int k=0;k<8;k++) r[k] = lda2(&g[k*512 + t]);
  #pragma unroll
  for (int k=0;k<8;k++) d[k*512 + t] = r[k];
}

// ---------------- prep: W_ih/W_hh (f32) -> fragment-major bf16 Wf [gs][nt<4][ks<32][lane][8] ----------------
__global__ void k_prep_w(const float* __restrict__ W_ih, const float* __restrict__ W_hh, u16* __restrict__ Wf){
  int idx = blockIdx.x*256 + threadIdx.x;        // 2,097,152
  int j    = idx & 7;
  int lane = (idx >> 3) & 63;
  int ks   = (idx >> 9) & 31;
  int nt   = (idx >> 14) & 3;
  int gs   = idx >> 16;                          // < 32
  int grow = nt*512 + gs*16 + (lane & 15);       // global gate row (nt = gate i/f/g/o)
  int k    = ks*32 + ((lane >> 4) & 3)*8 + j;    // 0..1023: [att 512 | h 512]
  float v = (k < 512) ? W_ih[grow*517 + k] : W_hh[grow*512 + (k - 512)];
  Wf[idx] = f2bf(v);
}
// ---------------- prep: K_conv (f32) -> fragment-major bf16 Kf [tap][nt<16][ks<16][lane][8] ----------------
__global__ void k_prep_kf(const float* __restrict__ Kc, u16* __restrict__ Kf){
  int idx = blockIdx.x*256 + threadIdx.x;        // 1,179,648
  int j    = idx & 7;
  int lane = (idx >> 3) & 63;
  int ks   = (idx >> 9) & 15;
  int nt   = (idx >> 13) & 15;
  int tap  = idx >> 17;                          // < 9
  int oc = nt*16 + (lane & 15);
  int ic = ks*32 + ((lane >> 4) & 3)*8 + j;
  Kf[idx] = f2bf(Kc[(oc*512 + ic)*9 + tap]);
}
// ---------------- prep: W_conv_h (f32) -> FULL fragment-major bf16 WcF2 [nt<16][ks<16][lane][8] ----------------
__global__ void k_prep_wcf2(const float* __restrict__ Wch, u16* __restrict__ WcF2){
  int idx = blockIdx.x*256 + threadIdx.x;        // 131,072
  int j = idx & 7, lane = (idx>>3) & 63, ks = (idx>>9) & 15, nt = idx >> 13;   // nt<16
  int e = nt*16 + (lane & 15);
  int k = ks*32 + ((lane >> 4) & 3)*8 + j;
  WcF2[idx] = f2bf(Wch[e*512 + k]);
}
// ---------------- prep: W_fc_params (f32) -> fragment-major bf16 WpF [ntile<8][ks<16][lane][8] ----------------
__global__ void k_prep_wp(const float* __restrict__ Wp, u16* __restrict__ WpF){
  int idx = blockIdx.x*256 + threadIdx.x;        // 65,536
  int j = idx & 7, lane = (idx>>3) & 63, ks = (idx>>9) & 15, ntile = idx >> 13;
  int n = ntile*16 + (lane & 15);
  int k = ks*32 + (lane >> 4)*8 + j;
  WpF[idx] = (n < 123) ? f2bf(Wp[n*512 + k]) : (u16)0;
}
// ---------------- init: hc = tanh(z @ W_fc_hc^T + b) -> h_pack (fragment-major bf16 pairs), c_ws (f32) ----------------
__global__ void k_hc(const float* __restrict__ z, const float* __restrict__ Wfc, const float* __restrict__ bfc,
                     u32* __restrict__ h_pack, float* __restrict__ c_ws){
  __shared__ float zl[128];
  int b = blockIdx.x, t = threadIdx.x;
  if (t < 128) zl[t] = z[b*128 + t];
  __syncthreads();
  float acc[4];
  #pragma unroll
  for (int i=0;i<4;i++){
    int n = 4*t + i;
    const float* row = Wfc + n*128;
    float a = 0.f;
    #pragma unroll 8
    for (int k2=0;k2<128;k2++) a += row[k2]*zl[k2];
    acc[i] = tanh_f(a + bfc[n]);
  }
  int bg = b >> 5, r = b & 31;
  if (t < 128){
    h_pack[bg*8192 + frag_a(r, 2*t)]   = packbf(acc[0], acc[1]);
    h_pack[bg*8192 + frag_a(r, 2*t+1)] = packbf(acc[2], acc[3]);
  } else {
    int base = 4*t - 512;
    #pragma unroll
    for (int i=0;i<4;i++) c_ws[b*512 + base + i] = acc[i];
  }
}
// ---------------- conv 3x3 SAME (f32 in, bf16 out) + bf16 backbone copy ----------------
__device__ __forceinline__ int xt_addr(int p, int chunk){ return p*512 + ((chunk ^ (p & 7))<<3); } // XOR-swizzled LDS
__global__ __launch_bounds__(256) void k_conv(const float* __restrict__ bb, const u16* __restrict__ Kf,
                       const float* __restrict__ bcf, u16* __restrict__ x_em, u16* __restrict__ bb_bf){
  __shared__ u16 xt[64*512];  // exactly 64KB, swizzled [p][ic]
  int b = blockIdx.x, t = threadIdx.x;
  const float* src = bb + (size_t)b*512*64;
  u16* dstc = bb_bf + (size_t)b*512*64;
  for (int i=0;i<128;i++){
    int idx = i*256 + t;
    int ic = idx >> 6, p = idx & 63;
    u16 v = f2bf(src[idx]);
    xt[xt_addr(p, ic>>3) + (ic&7)] = v;
    dstc[idx] = v;                         // bf16 copy, same [b][c][p] layout
  }
  __syncthreads();
  int wv = t >> 6, l = t & 63, c0 = l & 15, q = l >> 4;
  f32x4 acc[4][4];
  #pragma unroll
  for (int a=0;a<4;a++)
    #pragma unroll
    for (int bq=0;bq<4;bq++) acc[a][bq] = (f32x4)0.f;
  for (int tap=0; tap<9; ++tap){
    int ty = tap/3 - 1, tx = tap%3 - 1;
    for (int ks=0; ks<16; ++ks){
      bf16x8 afr[4];
      #pragma unroll
      for (int mt=0; mt<4; ++mt){
        int p = mt*16 + c0;
        int py = (p >> 3) + ty, px = (p & 7) + tx;
        if ((unsigned)py < 8u && (unsigned)px < 8u){
          afr[mt] = *(const bf16x8*)(&xt[xt_addr(py*8+px, ks*4 + q)]);
        } else {
          afr[mt] = (bf16x8)0;
        }
      }
      #pragma unroll
      for (int ni=0; ni<4; ++ni){
        int nt = wv*4 + ni;
        bf16x8 bfr = as_bf8(*(const u32x4*)(const void*)(Kf + (size_t)((((tap*16 + nt)*16 + ks)*64) + l)*8));
        #pragma unroll
        for (int mt=0; mt<4; ++mt)
          acc[mt][ni] = __builtin_amdgcn_mfma_f32_16x16x32_bf16(afr[mt], bfr, acc[mt][ni], 0,0,0);
      }
    }
  }
  #pragma unroll
  for (int ni=0; ni<4; ++ni){
    int e = (wv*4+ni)*16 + c0;
    float bias = bcf[e];
    #pragma unroll
    for (int mt=0; mt<4; ++mt)
      #pragma unroll
      for (int r=0;r<4;r++){
        int p = mt*16 + q*4 + r;
        x_em[(size_t)(b*256 + e)*64 + p] = f2bf(acc[mt][ni][r] + bias);
      }
  }
}

// ---------------- flag-array barrier, 16 partners per bg (one flag per 512-thread block).
// arrive: __syncthreads drains vmcnt(0) (all agent-scope data stores at coherence point) then one
// flag store. wait: wave-0 coalesced poll of the 16 flags (one line), syncthreads release. ----
__device__ __forceinline__ void bar_wait16(u32* flags, int bg, int t, u32 seq){
  if (t < 64){
    const u32* f = &flags[bg*64 + (t & 15)];
    for (;;){
      u32 v = lda1(f);
      if (__ballot(v < seq) == 0ull) break;
      __builtin_amdgcn_s_sleep(4);
    }
  }
  __atomic_signal_fence(__ATOMIC_ACQUIRE);   // compiler barrier: data loads stay after the spin
  __syncthreads();                            // release non-polling waves
}

// ---------------- head postprocess for one slice, parallelized over that slice's 256 threads ----------------
__device__ __forceinline__ void head_post_par(const float* yL, const float* __restrict__ bp,
                                              float* __restrict__ out, float* mrsL,
                                              int gs, int bg, int th, int step){
  const int CH = 1315840;          // 65792*20
  const int PEN = 7895040;         // 6*CH
  if (gs == 0 && th < 32){
    float m = -1e30f;
    #pragma unroll 1
    for (int c=3;c<23;c++){ float v = yL[th*33 + c] + bp[c]; m = fmaxf(m, v); }
    float su = 0.f;
    #pragma unroll 1
    for (int c=3;c<23;c++){ float v = yL[th*33 + c] + bp[c]; su += __builtin_amdgcn_exp2f((v-m)*L2E); }
    mrsL[th*2]   = m;
    mrsL[th*2+1] = __builtin_amdgcn_rcpf(su);
  }
  __syncthreads();
  int b = th >> 3, cb = (th & 7)*4;
  float m = mrsL[b*2], rs = mrsL[b*2+1];     // garbage unless gs==0; only used when ch==0 (gs==0)
  int rr = (bg*32 + b)*257 + step;
  #pragma unroll
  for (int i=0;i<4;i++){
    int c2 = cb + i;
    int col = gs*32 + c2;
    if (col >= 123) break;
    float v = yL[b*33 + c2] + bp[col];
    float tv; int oidx;
    if (col < 3){ tv = v; oidx = PEN + rr*3 + col; }
    else {
      int j = col - 3, ch = j/20, jj = j - ch*20;
      if (ch == 0)      tv = __builtin_amdgcn_exp2f((v-m)*L2E)*rs;
      else if (ch <= 2) tv = v;
      else if (ch <= 4) tv = __builtin_amdgcn_exp2f(v*L2E);
      else              tv = tanh_f(v);
      oidx = ch*CH + rr*20 + jj;
    }
    __builtin_nontemporal_store(tv, &out[oidx]);
  }
}
// head C for one slice (both halves of the block call together; block-wide syncthreads inside)
__device__ __forceinline__ void head_c(const u32* hF, const u16* __restrict__ WpF,
                                       const float* __restrict__ bp, float* __restrict__ outp,
                                       float* yL, float* mrsL, int gs, int bg, int t, int th, int step){
  int lane = t & 63, wv = th >> 6, c0 = lane & 15, q = lane >> 4;
  int mh = wv & 1, nt2 = wv >> 1;
  f32x4 ya = (f32x4)0.f;
  #pragma unroll 8
  for (int ks=0; ks<16; ++ks){
    bf16x8 bw = as_bf8(*(const u32x4*)(const void*)(WpF + (size_t)((((gs*2+nt2)*16 + ks)*64) + lane)*8));
    bf16x8 ah = *(const bf16x8*)(&hF[(ks*2 + mh)*256 + lane*4]);
    ya = __builtin_amdgcn_mfma_f32_16x16x32_bf16(ah, bw, ya, 0,0,0);
  }
  #pragma unroll
  for (int r=0;r<4;r++) yL[(mh*16 + q*4 + r)*33 + nt2*16 + c0] = ya[r];
  __syncthreads();
  head_post_par(yL, bp, outp, mrsL, gs, bg, th, step);
}

// ---------------- persistent RNN scan + fused head: 8 bg x 16 blocks x 512 threads.
// Each block owns TWO adjacent gs-slices (gs = gsp*2 + s, s = thread-half). The two slices share
// the staged h/att (halves exchange traffic) and the barrier (16 partners instead of 32). Phase
// bodies are R7-proven; 2 global barriers per step. ----------------
__global__ __launch_bounds__(512, 1) void k_rnn(
    const u16* __restrict__ bb_bf, const float* __restrict__ sketch,
    const float* __restrict__ b_ch, const float* __restrict__ Watt,
    const float* __restrict__ W_ih, const float* __restrict__ b_ih, const float* __restrict__ b_hh,
    const u16* __restrict__ x_em, const u16* __restrict__ Wf, const u16* __restrict__ WcF2,
    const u16* __restrict__ WpF, const float* __restrict__ bp,
    u32* __restrict__ h_pack, u32* __restrict__ att_pack,
    const float* __restrict__ c_ws, u32* __restrict__ flags, float* __restrict__ outp)
{
  __shared__ __align__(16) u32 hF[8192];       // 32KB: h fragments (shared by both slices)
  __shared__ __align__(16) u32 attF[8192];     // 32KB: att fragments (shared)
  __shared__ __align__(16) u16 x_emL[2][16384];// 64KB: per-slice x_em[ba]
  __shared__ __align__(16) u32 xaH[2][2112];   // 16.9KB: per-slice stgL/gbufL/yL+mrsL, phase-aliased
  __shared__ float gemA[2][256];
  __shared__ float wattA[256];
  __shared__ float bchA[256];
  __shared__ float alphaL[2][64];
  __shared__ float ptL[2][256];
  __shared__ float w5L[2][512];
  __shared__ float biasL[2][64];

  int t = threadIdx.x;
  int s  = t >> 8;                 // slice within block
  int th = t & 255;                // thread id within slice
  int pr = blockIdx.x >> 4, gsp = blockIdx.x & 15;
  int bg = pr;
  int gs = gsp*2 + s;
  int lane = t & 63, wv = th >> 6;
  int c0 = lane & 15, q = lane >> 4;
  float* stgL  = (float*)xaH[s];
  float* gbufL = (float*)xaH[s];
  float* yLs   = (float*)xaH[s];
  float* mrsLs = (float*)xaH[s] + 1056;

  // one-time staging
  if (t < 256){ wattA[t] = Watt[t]; bchA[t] = b_ch[t]; }
  if (th < 64){
    int grow = (th >> 4)*512 + gs*16 + (th & 15);
    biasL[s][th] = b_ih[grow] + b_hh[grow];
    #pragma unroll
    for (int d=0; d<5; ++d) w5L[s][th*8+d] = W_ih[grow*517 + 512 + d];
  }
  int bL = th & 31, hp = th >> 5;            // LSTM role within slice
  float c0r = c_ws[(bg*32 + bL)*512 + gs*16 + 2*hp];
  float c1r = c_ws[(bg*32 + bL)*512 + gs*16 + 2*hp + 1];
  int ba = bg*32 + gs;                       // own batch for this slice
  int mh_g = gs >> 4;
  int rq = (gs & 15) >> 2, rj = gs & 3;
  const u16* wb  = Wf   + (size_t)(((gs*4 + wv)*32)*64 + lane)*8;
  const u16* wcb = WcF2 + (size_t)((wv*4)*16*64 + lane)*8;
  const u32* hsrc = h_pack + (size_t)bg*8192;
  const u32* asrc = att_pack + (size_t)bg*8192;
  int hpub_a = frag_a(bL, gs*8 + hp);
  int apub_a = ((gs>>4)<<12) + ((th>>4)<<8) + (((th>>2)&3)<<6) + ((gs&15)<<2) + (th&3);
  u32* hpub = h_pack + (size_t)bg*8192 + hpub_a;
  u32* apub = att_pack + (size_t)bg*8192 + apub_a;
  // stage own slice's x_em (32KB = 2048 u32x4 = 8 per slice-thread; bounds per R3/R4 lesson)
  {
    const u32x4* xs = (const u32x4*)(x_em + (size_t)ba*16384);
    u32x4* xd = (u32x4*)x_emL[s];
    #pragma unroll
    for (int i=0;i<8;i++) xd[i*256 + th] = xs[i*256 + th];
  }
  // pt for ts=0 (start token)
  if (th < 32){
    ptL[s][th*8+0]=0.f; ptL[s][th*8+1]=0.f; ptL[s][th*8+2]=1.f; ptL[s][th*8+3]=0.f; ptL[s][th*8+4]=0.f;
  }
  u32 seq = 0;
  __syncthreads();

  #pragma clang loop unroll(disable)
  for (int ts=0; ts<257; ++ts){
    // guard hF WAR vs prev shadow-2 head-C reads
    __syncthreads();
    // ======== stage h(ts) (shared between slices; 512-thread batched agent loads) ========
    stage32h(hF, hsrc, t);
    __syncthreads();
    // ======== A-gem: duplicated g_em GEMM, keep own row ba (per slice) ========
    {
      f32x4 e0=(f32x4)0.f, e1=(f32x4)0.f, e2=(f32x4)0.f, e3=(f32x4)0.f;
      #pragma unroll 8
      for (int ks=0; ks<16; ++ks){
        bf16x8 hk = *(const bf16x8*)(&hF[(ks*2 + mh_g)*256 + lane*4]);
        bf16x8 b0 = as_bf8(*(const u32x4*)(const void*)(wcb + (size_t)(0*16 + ks)*512));
        bf16x8 b1 = as_bf8(*(const u32x4*)(const void*)(wcb + (size_t)(1*16 + ks)*512));
        bf16x8 b2 = as_bf8(*(const u32x4*)(const void*)(wcb + (size_t)(2*16 + ks)*512));
        bf16x8 b3 = as_bf8(*(const u32x4*)(const void*)(wcb + (size_t)(3*16 + ks)*512));
        e0 = __builtin_amdgcn_mfma_f32_16x16x32_bf16(hk, b0, e0, 0,0,0);
        e1 = __builtin_amdgcn_mfma_f32_16x16x32_bf16(hk, b1, e1, 0,0,0);
        e2 = __builtin_amdgcn_mfma_f32_16x16x32_bf16(hk, b2, e2, 0,0,0);
        e3 = __builtin_amdgcn_mfma_f32_16x16x32_bf16(hk, b3, e3, 0,0,0);
      }
      if (q == rq){
        gemA[s][(wv*4+0)*16 + c0] = e0[rj] + bchA[(wv*4+0)*16 + c0];
        gemA[s][(wv*4+1)*16 + c0] = e1[rj] + bchA[(wv*4+1)*16 + c0];
        gemA[s][(wv*4+2)*16 + c0] = e2[rj] + bchA[(wv*4+2)*16 + c0];
        gemA[s][(wv*4+3)*16 + c0] = e3[rj] + bchA[(wv*4+3)*16 + c0];
      }
    }
    __syncthreads();
    // ======== A-score: full 256-e scores for own batch from LDS x_em ========
    {
      int eg = th >> 3, ps = th & 7;
      float sp[8];
      #pragma unroll
      for (int j=0;j<8;j++) sp[j] = 0.f;
      const u16* xb = x_emL[s] + (size_t)(eg*8)*64 + ps*8;
      #pragma unroll
      for (int e2=0; e2<8; ++e2){
        float gev = gemA[s][eg*8 + e2];
        float wev = wattA[eg*8 + e2];
        bf16x8 xv = *(const bf16x8*)(xb + (size_t)e2*64);
        #pragma unroll
        for (int j=0;j<8;j++)
          sp[j] += tanh_f(bf2f((u16)xv[j]) + gev) * wev;
      }
      #pragma unroll
      for (int j=0;j<8;j++) stgL[eg*64 + ps*8 + j] = sp[j];
    }
    __syncthreads();
    if (th < 64){
      float sv = 0.f;
      #pragma unroll
      for (int g2=0; g2<32; ++g2) sv += stgL[g2*64 + th];
      float m = sv;
      #pragma unroll
      for (int d=1; d<64; d<<=1) m = fmaxf(m, __shfl_xor(m, d, 64));
      float ex = __builtin_amdgcn_exp2f((sv - m) * L2E);
      float su = ex;
      #pragma unroll
      for (int d=1; d<64; d<<=1) su += __shfl_xor(su, d, 64);
      alphaL[s][th] = ex * __builtin_amdgcn_rcpf(su);
    }
    __syncthreads();
    {  // att[c] = sum_p alpha[p]*backbone[ba][c][p]; slice-thread handles c = 2th, 2th+1
      const u16* base = bb_bf + (size_t)(ba*512 + 2*th)*64;
      float a0 = 0.f, a1 = 0.f;
      #pragma unroll
      for (int p8=0; p8<8; ++p8){
        bf16x8 v0 = *(const bf16x8*)(base + p8*8);
        bf16x8 v1 = *(const bf16x8*)(base + 64 + p8*8);
        #pragma unroll
        for (int j=0;j<8;j++){
          float al = alphaL[s][p8*8+j];
          a0 += al * bf2f((u16)v0[j]);
          a1 += al * bf2f((u16)v1[j]);
        }
      }
      sta(apub, packbf(a0, a1));
    }
    seq++;
    __syncthreads();               // drain att stores to coherence point
    if (t == 0) sta(&flags[bg*64 + gsp], seq);
    // ======== barrier-1 shadow: h-half gates (local hF, per-slice weights) ========
    f32x4 acc0 = (f32x4)0.f, acc1 = (f32x4)0.f;
    #pragma unroll 8
    for (int ks2=0; ks2<16; ++ks2){
      bf16x8 bfr = as_bf8(*(const u32x4*)(const void*)(wb + (size_t)(16+ks2)*512));
      bf16x8 a0 = *(const bf16x8*)(&hF[(ks2*2)*256 + lane*4]);
      bf16x8 a1 = *(const bf16x8*)(&hF[(ks2*2+1)*256 + lane*4]);
      acc0 = __builtin_amdgcn_mfma_f32_16x16x32_bf16(a0, bfr, acc0, 0,0,0);
      acc1 = __builtin_amdgcn_mfma_f32_16x16x32_bf16(a1, bfr, acc1, 0,0,0);
    }
    bar_wait16(flags, bg, t, seq);
    // ======== B: stage FULL att (shared) into attF; att-half gates; LSTM; publish h ========
    stage32h(attF, asrc, t);
    __syncthreads();
    #pragma unroll 8
    for (int kc=0; kc<16; ++kc){
      bf16x8 bfr = as_bf8(*(const u32x4*)(const void*)(wb + (size_t)kc*512));
      bf16x8 af0 = *(const bf16x8*)(&attF[kc*256 + lane*4]);
      bf16x8 af1 = *(const bf16x8*)(&attF[4096 + kc*256 + lane*4]);
      acc0 = __builtin_amdgcn_mfma_f32_16x16x32_bf16(af0, bfr, acc0, 0,0,0);
      acc1 = __builtin_amdgcn_mfma_f32_16x16x32_bf16(af1, bfr, acc1, 0,0,0);
    }
    {
      int n = wv*16 + c0;
      #pragma unroll
      for (int r=0;r<4;r++){
        gbufL[n*33 + (q*4 + r)]      = acc0[r];
        gbufL[n*33 + (16 + q*4 + r)] = acc1[r];
      }
    }
    __syncthreads();
    {
      const float* pl = ptL[s];
      float p0v = pl[bL*8+0], p1v = pl[bL*8+1], p2v = pl[bL*8+2], p3v = pl[bL*8+3], p4v = pl[bL*8+4];
      auto gval = [&](int n)->float {
        return gbufL[n*33 + bL] + biasL[s][n]
             + p0v*w5L[s][n*8+0] + p1v*w5L[s][n*8+1] + p2v*w5L[s][n*8+2] + p3v*w5L[s][n*8+3] + p4v*w5L[s][n*8+4];
      };
      float hv0 = 0.f, hv1 = 0.f;
      #pragma unroll
      for (int k2=0;k2<2;k2++){
        int hh = 2*hp + k2;
        float gi = gval(hh), gf = gval(16+hh), gg = gval(32+hh), go = gval(48+hh);
        float cp = k2 ? c1r : c0r;
        float cn = sig_f(gf)*cp + sig_f(gi)*tanh_f(gg);
        float hv = sig_f(go)*tanh_f(cn);
        if (k2){ c1r = cn; hv1 = hv; } else { c0r = cn; hv0 = hv; }
      }
      sta(hpub, packbf(hv0, hv1));
    }
    seq++;
    __syncthreads();               // drain h stores to coherence point
    if (t == 0) sta(&flags[bg*64 + gsp], seq);
    // ======== barrier-2 shadow: pt(ts+1); head C for output step ts-1 (hF = h_ts) ========
    if (ts < 256 && th < 32){
      const float* sp2 = sketch + ((size_t)ts*256 + bg*32 + th)*5;
      float* pl = ptL[s];
      pl[th*8+0]=sp2[0]; pl[th*8+1]=sp2[1]; pl[th*8+2]=sp2[2]; pl[th*8+3]=sp2[3]; pl[th*8+4]=sp2[4];
    }
    if (gsp < 2 && ts > 0){
      head_c(hF, WpF, bp, outp, yLs, mrsLs, gs, bg, t, th, ts-1);
    }
    bar_wait16(flags, bg, t, seq);
  }
  // ======== epilogue: head for step 256 (h_257 now in h_pack) ========
  if (gsp < 2){
    __syncthreads();
    stage32h(hF, hsrc, t);
    __syncthreads();
    head_c(hF, WpF, bp, outp, yLs, mrsLs, gs, bg, t, th, 256);
  }
}

extern "C" void kernel_launch(void* const* d_in, const int* in_sizes, int n_in,
                              void* d_out, int out_size, void* d_ws, size_t ws_size,
                              hipStream_t stream){
  (void)in_sizes; (void)n_in; (void)out_size; (void)ws_size;
  const float* backbone = (const float*)d_in[0];
  const float* z_vec    = (const float*)d_in[1];
  const float* sketch   = (const float*)d_in[2];
  const float* W_fc_hc  = (const float*)d_in[3];
  const float* b_fc_hc  = (const float*)d_in[4];
  const float* W_conv_h = (const float*)d_in[5];
  const float* b_conv_h = (const float*)d_in[6];
  const float* K_conv_f = (const float*)d_in[7];
  const float* b_conv_f = (const float*)d_in[8];
  const float* W_att    = (const float*)d_in[9];
  // d_in[10] = b_conv_att: additive constant to all scores -> softmax-invariant, skipped
  const float* W_ih     = (const float*)d_in[11];
  const float* W_hh     = (const float*)d_in[12];
  const float* b_ih     = (const float*)d_in[13];
  const float* b_hh     = (const float*)d_in[14];
  const float* W_fcp    = (const float*)d_in[15];
  const float* b_fcp    = (const float*)d_in[16];

  char* ws = (char*)d_ws;
  u32*   flags    = (u32*)(ws + 0);              // 16,384 (8 bg x 16 flags, 4B stride, 256B bg-stride)
  u32*   h_pack   = (u32*)(ws + 16384);          // 262,144 (fragment-major per bg)
  u32*   att_pack = (u32*)(ws + 278528);         // 262,144 (fragment-major per bg)
  float* c_ws     = (float*)(ws + 2637824);      // 524,288
  u16*   x_em     = (u16*)(ws + 3162112);        // 8,388,608
  u16*   Wf       = (u16*)(ws + 11550720);       // 4,194,304
  u16*   Kf       = (u16*)(ws + 15745024);       // 2,359,296
  u16*   WcF2     = (u16*)(ws + 18104320);       // 262,144
  u16*   WpF      = (u16*)(ws + 18628608);       // 131,072
  u16*   bb_bf    = (u16*)(ws + 18759680);       // 4,194,304

  (void)hipMemsetAsync(flags, 0, 16384, stream);
  k_prep_w  <<<8192, 256, 0, stream>>>(W_ih, W_hh, Wf);
  k_prep_kf <<<4608, 256, 0, stream>>>(K_conv_f, Kf);
  k_prep_wcf2<<<512, 256, 0, stream>>>(W_conv_h, WcF2);
  k_prep_wp <<<256,  256, 0, stream>>>(W_fcp, WpF);
  k_hc      <<<256,  256, 0, stream>>>(z_vec, W_fc_hc, b_fc_hc, h_pack, c_ws);
  k_conv    <<<256,  256, 0, stream>>>(backbone, Kf, b_conv_f, x_em, bb_bf);
  k_rnn     <<<128,  512, 0, stream>>>(bb_bf, sketch, b_conv_h, W_att, W_ih, b_ih, b_hh,
                                       x_em, Wf, WcF2, WpF, b_fcp,
                                       h_pack, att_pack, c_ws, flags, (float*)d_out);
}

// Round 11
// 4898.794 us; speedup vs baseline: 5.3153x; 2.2318x over previous
//
#include <hip/hip_runtime.h>
#include <hip/hip_bf16.h>

typedef unsigned short u16;
typedef unsigned int   u32;
typedef unsigned long long u64;

typedef __attribute__((ext_vector_type(8))) short bf16x8;  // 8 x bf16 (4 VGPR) MFMA A/B frag
typedef __attribute__((ext_vector_type(4))) float f32x4;   // MFMA C/D frag
typedef __attribute__((ext_vector_type(4))) u32   u32x4;

#define L2E 1.44269504088896340736f

__device__ __forceinline__ float bf2f(u16 u){ union{u32 i; float f;} v; v.i=((u32)u)<<16; return v.f; }
__device__ __forceinline__ u16  f2bf(float f){ union{float f; u32 i;} v; v.f=f; u32 u=v.i; return (u16)((u + 0x7fffu + ((u>>16)&1u))>>16); }
__device__ __forceinline__ u32  packbf(float a,float b){ return (u32)f2bf(a) | ((u32)f2bf(b)<<16); }
__device__ __forceinline__ float tanh_f(float x){
  float cx = fminf(fmaxf(x,-15.f),15.f);
  float e  = __builtin_amdgcn_exp2f(cx*(2.f*L2E));
  return (e-1.f)*__builtin_amdgcn_rcpf(e+1.f);
}
__device__ __forceinline__ float sig_f(float x){
  float cx = fminf(fmaxf(x,-30.f),30.f);
  float e  = __builtin_amdgcn_exp2f(-cx*L2E);
  return __builtin_amdgcn_rcpf(1.f+e);
}
// Cross-XCD coherent accesses: relaxed agent-scope atomics (bypass per-XCD caches; L3 = coherence point).
__device__ __forceinline__ u64   lda2(const u64* p){ return __hip_atomic_load((u64*)p, __ATOMIC_RELAXED, __HIP_MEMORY_SCOPE_AGENT); }
__device__ __forceinline__ u32   lda1(const u32* p){ return __hip_atomic_load((u32*)p, __ATOMIC_RELAXED, __HIP_MEMORY_SCOPE_AGENT); }
__device__ __forceinline__ void  sta(u32* p, u32 v){ __hip_atomic_store(p, v, __ATOMIC_RELAXED, __HIP_MEMORY_SCOPE_AGENT); }
__device__ __forceinline__ bf16x8 as_bf8(u32x4 w){ union{u32x4 u; bf16x8 b;} c; c.u=w; return c.b; }
// fragment-major address for an h element pair: batch r, u32-col c (h element pair 2c,2c+1)
__device__ __forceinline__ int frag_a(int r, int c){
  return ((c>>4)*2 + (r>>4))*256 + (((c>>2)&3))*64 + ((r&15))*4 + (c&3);
}

// ---- batched 32KB L3->LDS stage (dense image copy): 16 u64 agent loads in flight, 16 ds_write_b64 ----
__device__ __forceinline__ void stage32i(u32* lds, const u32* gsrc, int t){
  const u64* g = (const u64*)gsrc;
  u64* d = (u64*)lds;
  u64 r[16];
  #pragma unroll
  for (int k=0;k<16;k++) r[k] = lda2(&g[k*256 + t]);
  #pragma unroll
  for (int k=0;k<16;k++) d[k*256 + t] = r[k];
}
// ---- att stage: global batch-major [r<32][pair<256] -> att-fragment LDS image.
// Thread t, iter k loads u64 at u32-offset k*512+2t (coalesced): batch r=2k+(t>>7), pairs p0=2t&255,p0+1.
// LDS image afrag(r,p) = ((r>>4)<<12)+((p>>4)<<8)+(((p>>2)&3)<<6)+((r&15)<<2)+(p&3) — identical to the
// image the old dense copy produced; afrag(r,p0+1)==afrag(r,p0)+1 for even p0 -> one ds_write_b64. ----
__device__ __forceinline__ void stage_att(u32* lds, const u32* gsrc, int t){
  const u64* g = (const u64*)gsrc;
  u64 r[16];
  #pragma unroll
  for (int k=0;k<16;k++) r[k] = lda2(&g[k*256 + t]);
  #pragma unroll
  for (int k=0;k<16;k++){
    int o  = k*512 + 2*t;
    int rr = o >> 8, p0 = o & 255;
    int a  = ((rr>>4)<<12) + ((p0>>4)<<8) + (((p0>>2)&3)<<6) + ((rr&15)<<2) + (p0&3);
    *(u64*)&lds[a] = r[k];
  }
}

// ---------------- prep: W_ih/W_hh (f32) -> fragment-major bf16 Wf [gs][nt<4][ks<32][lane][8] ----------------
__global__ void k_prep_w(const float* __restrict__ W_ih, const float* __restrict__ W_hh, u16* __restrict__ Wf){
  int idx = blockIdx.x*256 + threadIdx.x;        // 2,097,152
  int j    = idx & 7;
  int lane = (idx >> 3) & 63;
  int ks   = (idx >> 9) & 31;
  int nt   = (idx >> 14) & 3;
  int gs   = idx >> 16;                          // < 32
  int grow = nt*512 + gs*16 + (lane & 15);       // global gate row (nt = gate i/f/g/o)
  int k    = ks*32 + ((lane >> 4) & 3)*8 + j;    // 0..1023: [att 512 | h 512]
  float v = (k < 512) ? W_ih[grow*517 + k] : W_hh[grow*512 + (k - 512)];
  Wf[idx] = f2bf(v);
}
// ---------------- prep: K_conv (f32) -> fragment-major bf16 Kf [tap][nt<16][ks<16][lane][8] ----------------
__global__ void k_prep_kf(const float* __restrict__ Kc, u16* __restrict__ Kf){
  int idx = blockIdx.x*256 + threadIdx.x;        // 1,179,648
  int j    = idx & 7;
  int lane = (idx >> 3) & 63;
  int ks   = (idx >> 9) & 15;
  int nt   = (idx >> 13) & 15;
  int tap  = idx >> 17;                          // < 9
  int oc = nt*16 + (lane & 15);
  int ic = ks*32 + ((lane >> 4) & 3)*8 + j;
  Kf[idx] = f2bf(Kc[(oc*512 + ic)*9 + tap]);
}
// ---------------- prep: W_conv_h (f32) -> FULL fragment-major bf16 WcF2 [nt<16][ks<16][lane][8] ----------------
__global__ void k_prep_wcf2(const float* __restrict__ Wch, u16* __restrict__ WcF2){
  int idx = blockIdx.x*256 + threadIdx.x;        // 131,072
  int j = idx & 7, lane = (idx>>3) & 63, ks = (idx>>9) & 15, nt = idx >> 13;   // nt<16
  int e = nt*16 + (lane & 15);
  int k = ks*32 + ((lane >> 4) & 3)*8 + j;
  WcF2[idx] = f2bf(Wch[e*512 + k]);
}
// ---------------- prep: W_fc_params (f32) -> fragment-major bf16 WpF [ntile<8][ks<16][lane][8] ----------------
__global__ void k_prep_wp(const float* __restrict__ Wp, u16* __restrict__ WpF){
  int idx = blockIdx.x*256 + threadIdx.x;        // 65,536
  int j = idx & 7, lane = (idx>>3) & 63, ks = (idx>>9) & 15, ntile = idx >> 13;
  int n = ntile*16 + (lane & 15);
  int k = ks*32 + (lane >> 4)*8 + j;
  WpF[idx] = (n < 123) ? f2bf(Wp[n*512 + k]) : (u16)0;
}
// ---------------- init: hc = tanh(z @ W_fc_hc^T + b) -> h_pack (fragment-major bf16 pairs), c_ws (f32) ----------------
__global__ void k_hc(const float* __restrict__ z, const float* __restrict__ Wfc, const float* __restrict__ bfc,
                     u32* __restrict__ h_pack, float* __restrict__ c_ws){
  __shared__ float zl[128];
  int b = blockIdx.x, t = threadIdx.x;
  if (t < 128) zl[t] = z[b*128 + t];
  __syncthreads();
  float acc[4];
  #pragma unroll
  for (int i=0;i<4;i++){
    int n = 4*t + i;
    const float* row = Wfc + n*128;
    float a = 0.f;
    #pragma unroll 8
    for (int k2=0;k2<128;k2++) a += row[k2]*zl[k2];
    acc[i] = tanh_f(a + bfc[n]);
  }
  int bg = b >> 5, r = b & 31;
  if (t < 128){
    h_pack[bg*8192 + frag_a(r, 2*t)]   = packbf(acc[0], acc[1]);
    h_pack[bg*8192 + frag_a(r, 2*t+1)] = packbf(acc[2], acc[3]);
  } else {
    int base = 4*t - 512;
    #pragma unroll
    for (int i=0;i<4;i++) c_ws[b*512 + base + i] = acc[i];
  }
}
// ---------------- conv 3x3 SAME (f32 in, bf16 out) + bf16 backbone copy ----------------
__device__ __forceinline__ int xt_addr(int p, int chunk){ return p*512 + ((chunk ^ (p & 7))<<3); } // XOR-swizzled LDS
__global__ __launch_bounds__(256) void k_conv(const float* __restrict__ bb, const u16* __restrict__ Kf,
                       const float* __restrict__ bcf, u16* __restrict__ x_em, u16* __restrict__ bb_bf){
  __shared__ u16 xt[64*512];  // exactly 64KB, swizzled [p][ic]
  int b = blockIdx.x, t = threadIdx.x;
  const float* src = bb + (size_t)b*512*64;
  u16* dstc = bb_bf + (size_t)b*512*64;
  for (int i=0;i<128;i++){
    int idx = i*256 + t;
    int ic = idx >> 6, p = idx & 63;
    u16 v = f2bf(src[idx]);
    xt[xt_addr(p, ic>>3) + (ic&7)] = v;
    dstc[idx] = v;                         // bf16 copy, same [b][c][p] layout
  }
  __syncthreads();
  int wv = t >> 6, l = t & 63, c0 = l & 15, q = l >> 4;
  f32x4 acc[4][4];
  #pragma unroll
  for (int a=0;a<4;a++)
    #pragma unroll
    for (int bq=0;bq<4;bq++) acc[a][bq] = (f32x4)0.f;
  for (int tap=0; tap<9; ++tap){
    int ty = tap/3 - 1, tx = tap%3 - 1;
    for (int ks=0; ks<16; ++ks){
      bf16x8 afr[4];
      #pragma unroll
      for (int mt=0; mt<4; ++mt){
        int p = mt*16 + c0;
        int py = (p >> 3) + ty, px = (p & 7) + tx;
        if ((unsigned)py < 8u && (unsigned)px < 8u){
          afr[mt] = *(const bf16x8*)(&xt[xt_addr(py*8+px, ks*4 + q)]);
        } else {
          afr[mt] = (bf16x8)0;
        }
      }
      #pragma unroll
      for (int ni=0; ni<4; ++ni){
        int nt = wv*4 + ni;
        bf16x8 bfr = as_bf8(*(const u32x4*)(const void*)(Kf + (size_t)((((tap*16 + nt)*16 + ks)*64) + l)*8));
        #pragma unroll
        for (int mt=0; mt<4; ++mt)
          acc[mt][ni] = __builtin_amdgcn_mfma_f32_16x16x32_bf16(afr[mt], bfr, acc[mt][ni], 0,0,0);
      }
    }
  }
  #pragma unroll
  for (int ni=0; ni<4; ++ni){
    int e = (wv*4+ni)*16 + c0;
    float bias = bcf[e];
    #pragma unroll
    for (int mt=0; mt<4; ++mt)
      #pragma unroll
      for (int r=0;r<4;r++){
        int p = mt*16 + q*4 + r;
        x_em[(size_t)(b*256 + e)*64 + p] = f2bf(acc[mt][ni][r] + bias);
      }
  }
}

// ---------------- flag-array barrier (R6/R7-proven): 32 plain relaxed stores to distinct 4B slots;
// poll by WAVE 0 ONLY (coalesced ballot over the 32 flags), s_sleep(4) backoff, __syncthreads release.
// arrive-side __syncthreads drains vmcnt(0): all agent-scope data stores at the coherence point
// before the flag store issues. ----
__device__ __forceinline__ void bar_arrive(u32* flags, int bg, int gs, int t, u32 seq){
  __syncthreads();   // all waves' agent-scope data stores acked at coherence point
  if (t == 0) sta(&flags[bg*64 + gs], seq);
}
__device__ __forceinline__ void bar_wait(u32* flags, int bg, int t, u32 seq){
  if (t < 32){
    const u32* f = &flags[bg*64 + t];
    for (;;){
      u32 v = lda1(f);
      if (__ballot(v < seq) == 0ull) break;
      __builtin_amdgcn_s_sleep(4);
    }
  }
  __atomic_signal_fence(__ATOMIC_ACQUIRE);   // compiler barrier: data loads stay after the spin
  __syncthreads();                            // release non-polling waves
}

// ---------------- head postprocess, parallelized over all 256 threads ----------------
__device__ __forceinline__ void head_post_par(const float* yL, const float* __restrict__ bp,
                                              float* __restrict__ out, float* mrsL,
                                              int gs, int bg, int t, int step){
  const int CH = 1315840;          // 65792*20
  const int PEN = 7895040;         // 6*CH
  if (gs == 0 && t < 32){
    float m = -1e30f;
    #pragma unroll 1
    for (int c=3;c<23;c++){ float v = yL[t*33 + c] + bp[c]; m = fmaxf(m, v); }
    float su = 0.f;
    #pragma unroll 1
    for (int c=3;c<23;c++){ float v = yL[t*33 + c] + bp[c]; su += __builtin_amdgcn_exp2f((v-m)*L2E); }
    mrsL[t*2]   = m;
    mrsL[t*2+1] = __builtin_amdgcn_rcpf(su);
  }
  __syncthreads();
  int b = t >> 3, cb = (t & 7)*4;
  float m = mrsL[b*2], rs = mrsL[b*2+1];
  int rr = (bg*32 + b)*257 + step;
  #pragma unroll
  for (int i=0;i<4;i++){
    int c2 = cb + i;
    int col = gs*32 + c2;
    if (col >= 123) break;
    float v = yL[b*33 + c2] + bp[col];
    float tv; int oidx;
    if (col < 3){ tv = v; oidx = PEN + rr*3 + col; }
    else {
      int j = col - 3, ch = j/20, jj = j - ch*20;
      if (ch == 0)      tv = __builtin_amdgcn_exp2f((v-m)*L2E)*rs;
      else if (ch <= 2) tv = v;
      else if (ch <= 4) tv = __builtin_amdgcn_exp2f(v*L2E);
      else              tv = tanh_f(v);
      oidx = ch*CH + rr*20 + jj;
    }
    __builtin_nontemporal_store(tv, &out[oidx]);
  }
}

// ---------------- persistent RNN scan + fused head: 8 bg-groups x 32 gs-blocks, 2 barriers/step ----------------
__global__ __launch_bounds__(256, 1) void k_rnn(
    const u16* __restrict__ bb_bf, const float* __restrict__ sketch,
    const float* __restrict__ b_ch, const float* __restrict__ Watt,
    const float* __restrict__ W_ih, const float* __restrict__ b_ih, const float* __restrict__ b_hh,
    const u16* __restrict__ x_em, const u16* __restrict__ Wf, const u16* __restrict__ WcF2,
    const u16* __restrict__ WpF, const float* __restrict__ bp,
    u32* __restrict__ h_pack, u32* __restrict__ att_pack,
    const float* __restrict__ c_ws, u32* __restrict__ flags, float* __restrict__ outp)
{
  __shared__ __align__(16) u32 hF[8192];     // 32KB: h fragments, valid the whole iteration
  __shared__ __align__(16) u32 attF[8192];   // 32KB: att fragments (own buffer -> hF survives for head C)
  __shared__ __align__(16) u32 xaH[4096];    // 16KB: score staging (8KB) / gates buffer (8.4KB), phase-aliased
  __shared__ __align__(16) u16 x_emL[16384]; // 32KB: step-invariant x_em[ba] staged ONCE ([e<256][p<64])
  __shared__ float gemA[256];     // g_em row for own batch (bias folded); re-used as h-publish exchange
  __shared__ float wattA[256];
  __shared__ float bchA[256];
  __shared__ float alphaL[64];
  __shared__ float ptL[32*8];
  __shared__ float w5L[64*8];
  __shared__ float biasL[64];
  __shared__ float yL[32*33];     // head y staging (4.2KB)
  __shared__ float mrsL[64];
  float* gbufL = (float*)xaH;
  float* stgL  = (float*)xaH;

  int t = threadIdx.x;
  int bg = blockIdx.x >> 5, gs = blockIdx.x & 31;
  int lane = t & 63, wv = t >> 6;
  int c0 = lane & 15, q = lane >> 4;

  // one-time staging
  wattA[t] = Watt[t];
  bchA[t]  = b_ch[t];
  if (t < 64){
    int grow = (t >> 4)*512 + gs*16 + (t & 15);
    biasL[t] = b_ih[grow] + b_hh[grow];
    #pragma unroll
    for (int d=0; d<5; ++d) w5L[t*8+d] = W_ih[grow*517 + 512 + d];
  }
  int bL = t & 31, hp = t >> 5;              // LSTM role
  int gb_l = bg*32 + bL;
  float c0r = c_ws[gb_l*512 + gs*16 + 2*hp];
  float c1r = c_ws[gb_l*512 + gs*16 + 2*hp + 1];
  int ba = bg*32 + gs;                       // own batch
  int mh_g = gs >> 4;                        // m-half holding our batch row
  int rq = (gs & 15) >> 2, rj = gs & 3;      // quad / reg of our row in the C-frag
  const u16* wb  = Wf   + (size_t)(((gs*4 + wv)*32)*64 + lane)*8;
  const u16* wcb = WcF2 + (size_t)((wv*4)*16*64 + lane)*8;   // g_em weight base for ni=0
  const u32* hsrc = h_pack + (size_t)bg*8192;
  const u32* asrc = att_pack + (size_t)bg*8192;
  u32* apub = att_pack + (size_t)bg*8192 + gs*256 + t;   // batch-major att publish: coalesced 1KB/block
  // step-invariant gate weights -> REGISTERS (128 VGPR; 1 wave/SIMD so the file is half empty).
  bf16x8 wfA[16], wfH[16];
  #pragma unroll
  for (int k=0;k<16;k++){
    wfA[k] = as_bf8(*(const u32x4*)(const void*)(wb + (size_t)k*512));
    wfH[k] = as_bf8(*(const u32x4*)(const void*)(wb + (size_t)(16+k)*512));
  }
  // stage x_em[ba] (step-invariant, 32KB = 2048 u32x4) into LDS: 8 per thread (bounds-checked!)
  {
    const u32x4* xs = (const u32x4*)(x_em + (size_t)ba*16384);
    u32x4* xd = (u32x4*)x_emL;
    #pragma unroll
    for (int i=0;i<8;i++) xd[i*256 + t] = xs[i*256 + t];
  }
  // pre-stage pt for ts=0 (start token)
  if (t < 32){
    ptL[t*8+0]=0.f; ptL[t*8+1]=0.f; ptL[t*8+2]=1.f; ptL[t*8+3]=0.f; ptL[t*8+4]=0.f;
  }
  u32 seq = 0;
  __syncthreads();

  #pragma clang loop unroll(disable)
  for (int ts=0; ts<257; ++ts){
    // guard hF WAR: head C (bar2 shadow of prev iter) read hF; all waves passed bar2-wait
    __syncthreads();
    // ======== stage h: batched coalesced agent-scope loads -> LDS (one latency epoch) ========
    stage32i(hF, hsrc, t);
    __syncthreads();
    // ======== A-gem: duplicated g_em GEMM (32x256x512), keep only own row ba ========
    {
      f32x4 ge0 = (f32x4)0.f, ge1 = (f32x4)0.f, ge2 = (f32x4)0.f, ge3 = (f32x4)0.f;
      #pragma unroll 8
      for (int ks=0; ks<16; ++ks){
        bf16x8 ahk = *(const bf16x8*)(&hF[(ks*2 + mh_g)*256 + lane*4]);
        bf16x8 b0 = as_bf8(*(const u32x4*)(const void*)(wcb + (size_t)(0*16 + ks)*512));
        bf16x8 b1 = as_bf8(*(const u32x4*)(const void*)(wcb + (size_t)(1*16 + ks)*512));
        bf16x8 b2 = as_bf8(*(const u32x4*)(const void*)(wcb + (size_t)(2*16 + ks)*512));
        bf16x8 b3 = as_bf8(*(const u32x4*)(const void*)(wcb + (size_t)(3*16 + ks)*512));
        ge0 = __builtin_amdgcn_mfma_f32_16x16x32_bf16(ahk, b0, ge0, 0,0,0);
        ge1 = __builtin_amdgcn_mfma_f32_16x16x32_bf16(ahk, b1, ge1, 0,0,0);
        ge2 = __builtin_amdgcn_mfma_f32_16x16x32_bf16(ahk, b2, ge2, 0,0,0);
        ge3 = __builtin_amdgcn_mfma_f32_16x16x32_bf16(ahk, b3, ge3, 0,0,0);
      }
      if (q == rq){
        gemA[(wv*4+0)*16 + c0] = ge0[rj] + bchA[(wv*4+0)*16 + c0];
        gemA[(wv*4+1)*16 + c0] = ge1[rj] + bchA[(wv*4+1)*16 + c0];
        gemA[(wv*4+2)*16 + c0] = ge2[rj] + bchA[(wv*4+2)*16 + c0];
        gemA[(wv*4+3)*16 + c0] = ge3[rj] + bchA[(wv*4+3)*16 + c0];
      }
    }
    __syncthreads();
    // ======== A-score: full 256-e scores for OWN batch from LDS x_em; thread=(e-group eg, p-octet ps) ========
    {
      int eg = t >> 3, ps = t & 7;
      float sp[8];
      #pragma unroll
      for (int j=0;j<8;j++) sp[j] = 0.f;
      const u16* xb = x_emL + (size_t)(eg*8)*64 + ps*8;
      #pragma unroll
      for (int e2=0; e2<8; ++e2){
        float gev = gemA[eg*8 + e2];
        float wev = wattA[eg*8 + e2];
        bf16x8 xv = *(const bf16x8*)(xb + (size_t)e2*64);
        #pragma unroll
        for (int j=0;j<8;j++)
          sp[j] += tanh_f(bf2f((u16)xv[j]) + gev) * wev;
      }
      #pragma unroll
      for (int j=0;j<8;j++) stgL[eg*64 + ps*8 + j] = sp[j];
    }
    __syncthreads();
    if (t < 64){
      float s = 0.f;
      #pragma unroll
      for (int g2=0; g2<32; ++g2) s += stgL[g2*64 + t];
      float m = s;
      #pragma unroll
      for (int d=1; d<64; d<<=1) m = fmaxf(m, __shfl_xor(m, d, 64));
      float ex = __builtin_amdgcn_exp2f((s - m) * L2E);
      float su = ex;
      #pragma unroll
      for (int d=1; d<64; d<<=1) su += __shfl_xor(su, d, 64);
      alphaL[t] = ex * __builtin_amdgcn_rcpf(su);
    }
    __syncthreads();
    {  // att[c] = sum_p alpha[p]*backbone[ba][c][p]; thread handles c = 2t, 2t+1 -> pair index t
      const u16* base = bb_bf + (size_t)(ba*512 + 2*t)*64;
      float a0 = 0.f, a1 = 0.f;
      #pragma unroll
      for (int p8=0; p8<8; ++p8){
        bf16x8 v0 = *(const bf16x8*)(base + p8*8);
        bf16x8 v1 = *(const bf16x8*)(base + 64 + p8*8);
        #pragma unroll
        for (int j=0;j<8;j++){
          float al = alphaL[p8*8+j];
          a0 += al * bf2f((u16)v0[j]);
          a1 += al * bf2f((u16)v1[j]);
        }
      }
      sta(apub, packbf(a0, a1));   // batch-major: block stores 1KB contiguous (zero amplification)
    }
    seq++; bar_arrive(flags, bg, gs, t, seq);
    // ======== barrier-1 shadow: h-half gates (register weights; local hF only) ========
    f32x4 acc0 = (f32x4)0.f, acc1 = (f32x4)0.f;
    #pragma unroll
    for (int ks2=0; ks2<16; ++ks2){
      bf16x8 a0 = *(const bf16x8*)(&hF[(ks2*2)*256 + lane*4]);
      bf16x8 a1 = *(const bf16x8*)(&hF[(ks2*2+1)*256 + lane*4]);
      acc0 = __builtin_amdgcn_mfma_f32_16x16x32_bf16(a0, wfH[ks2], acc0, 0,0,0);
      acc1 = __builtin_amdgcn_mfma_f32_16x16x32_bf16(a1, wfH[ks2], acc1, 0,0,0);
    }
    bar_wait(flags, bg, t, seq);
    // ======== B: stage FULL att (batch-major -> fragment image) into attF; att-half gates; LSTM ========
    stage_att(attF, asrc, t);
    __syncthreads();
    #pragma unroll
    for (int kc=0; kc<16; ++kc){
      bf16x8 af0 = *(const bf16x8*)(&attF[kc*256 + lane*4]);
      bf16x8 af1 = *(const bf16x8*)(&attF[4096 + kc*256 + lane*4]);
      acc0 = __builtin_amdgcn_mfma_f32_16x16x32_bf16(af0, wfA[kc], acc0, 0,0,0);
      acc1 = __builtin_amdgcn_mfma_f32_16x16x32_bf16(af1, wfA[kc], acc1, 0,0,0);
    }
    {
      int n = wv*16 + c0;
      #pragma unroll
      for (int r=0;r<4;r++){
        gbufL[n*33 + (q*4 + r)]      = acc0[r];
        gbufL[n*33 + (16 + q*4 + r)] = acc1[r];
      }
    }
    __syncthreads();
    {
      float p0v = ptL[bL*8+0], p1v = ptL[bL*8+1], p2v = ptL[bL*8+2], p3v = ptL[bL*8+3], p4v = ptL[bL*8+4];
      auto gval = [&](int n)->float {
        return gbufL[n*33 + bL] + biasL[n]
             + p0v*w5L[n*8+0] + p1v*w5L[n*8+1] + p2v*w5L[n*8+2] + p3v*w5L[n*8+3] + p4v*w5L[n*8+4];
      };
      float hv0 = 0.f, hv1 = 0.f;
      #pragma unroll
      for (int k2=0;k2<2;k2++){
        int hh = 2*hp + k2;
        float gi = gval(hh), gf = gval(16+hh), gg = gval(32+hh), go = gval(48+hh);
        float cp = k2 ? c1r : c0r;
        float cn = sig_f(gf)*cp + sig_f(gi)*tanh_f(gg);
        float hv = sig_f(go)*tanh_f(cn);
        if (k2){ c1r = cn; hv1 = hv; } else { c0r = cn; hv0 = hv; }
      }
      // h publish via LDS exchange (gemA is dead this phase): producer writes value for (bL,hp);
      // then 4x256B fully-coalesced fragment-major chunks (same address SET as the old scatter).
      ((u32*)gemA)[hp*32 + bL] = packbf(hv0, hv1);
    }
    __syncthreads();
    {
      int chunk = t >> 6, off = t & 63;
      int tb = chunk >> 1, qb = chunk & 1;
      int rr2 = tb*16 + (off >> 2), hpp = qb*4 + (off & 3);
      u32 v = ((u32*)gemA)[hpp*32 + rr2];
      int T2 = (gs >> 1)*2 + tb, q22 = (gs & 1)*2 + qb;
      sta(h_pack + (size_t)bg*8192 + T2*256 + q22*64 + off, v);
    }
    seq++; bar_arrive(flags, bg, gs, t, seq);
    // ======== barrier-2 shadow: pt for ts+1; head C for output step ts-1 (hF still = h_{ts-1}) ========
    if (ts < 256 && t < 32){
      const float* sp = sketch + ((size_t)ts*256 + (bg*32 + t))*5;
      ptL[t*8+0]=sp[0]; ptL[t*8+1]=sp[1]; ptL[t*8+2]=sp[2]; ptL[t*8+3]=sp[3]; ptL[t*8+4]=sp[4];
    }
    if (gs < 4 && ts > 0){
      int mh = wv & 1, nt2 = wv >> 1;
      f32x4 ya = (f32x4)0.f;
      #pragma unroll 8
      for (int ks=0; ks<16; ++ks){
        bf16x8 bw = as_bf8(*(const u32x4*)(const void*)(WpF + (size_t)((((gs*2+nt2)*16 + ks)*64) + lane)*8));
        bf16x8 ah = *(const bf16x8*)(&hF[(ks*2 + mh)*256 + lane*4]);
        ya = __builtin_amdgcn_mfma_f32_16x16x32_bf16(ah, bw, ya, 0,0,0);
      }
      #pragma unroll
      for (int r=0;r<4;r++) yL[(mh*16 + q*4 + r)*33 + nt2*16 + c0] = ya[r];
      __syncthreads();
      head_post_par(yL, bp, outp, mrsL, gs, bg, t, ts-1);
    }
    bar_wait(flags, bg, t, seq);
  }
  // ======== epilogue: head for step 256 (h_256 now in h_pack) ========
  if (gs < 4){
    __syncthreads();
    stage32i(hF, hsrc, t);
    __syncthreads();
    int mh = wv & 1, nt2 = wv >> 1;
    f32x4 ya = (f32x4)0.f;
    #pragma unroll 8
    for (int ks=0; ks<16; ++ks){
      bf16x8 bw = as_bf8(*(const u32x4*)(const void*)(WpF + (size_t)((((gs*2+nt2)*16 + ks)*64) + lane)*8));
      bf16x8 ah = *(const bf16x8*)(&hF[(ks*2 + mh)*256 + lane*4]);
      ya = __builtin_amdgcn_mfma_f32_16x16x32_bf16(ah, bw, ya, 0,0,0);
    }
    #pragma unroll
    for (int r=0;r<4;r++) yL[(mh*16 + q*4 + r)*33 + nt2*16 + c0] = ya[r];
    __syncthreads();
    head_post_par(yL, bp, outp, mrsL, gs, bg, t, 256);
  }
}

extern "C" void kernel_launch(void* const* d_in, const int* in_sizes, int n_in,
                              void* d_out, int out_size, void* d_ws, size_t ws_size,
                              hipStream_t stream){
  (void)in_sizes; (void)n_in; (void)out_size; (void)ws_size;
  const float* backbone = (const float*)d_in[0];
  const float* z_vec    = (const float*)d_in[1];
  const float* sketch   = (const float*)d_in[2];
  const float* W_fc_hc  = (const float*)d_in[3];
  const float* b_fc_hc  = (const float*)d_in[4];
  const float* W_conv_h = (const float*)d_in[5];
  const float* b_conv_h = (const float*)d_in[6];
  const float* K_conv_f = (const float*)d_in[7];
  const float* b_conv_f = (const float*)d_in[8];
  const float* W_att    = (const float*)d_in[9];
  // d_in[10] = b_conv_att: additive constant to all scores -> softmax-invariant, skipped
  const float* W_ih     = (const float*)d_in[11];
  const float* W_hh     = (const float*)d_in[12];
  const float* b_ih     = (const float*)d_in[13];
  const float* b_hh     = (const float*)d_in[14];
  const float* W_fcp    = (const float*)d_in[15];
  const float* b_fcp    = (const float*)d_in[16];

  char* ws = (char*)d_ws;
  u32*   flags    = (u32*)(ws + 0);              // 16,384 (8 bg x 32 flags, 4B stride)
  u32*   h_pack   = (u32*)(ws + 16384);          // 262,144 (fragment-major per bg)
  u32*   att_pack = (u32*)(ws + 278528);         // 262,144 (batch-major per bg)
  float* c_ws     = (float*)(ws + 2637824);      // 524,288
  u16*   x_em     = (u16*)(ws + 3162112);        // 8,388,608
  u16*   Wf       = (u16*)(ws + 11550720);       // 4,194,304
  u16*   Kf       = (u16*)(ws + 15745024);       // 2,359,296
  u16*   WcF2     = (u16*)(ws + 18104320);       // 262,144
  u16*   WpF      = (u16*)(ws + 18628608);       // 131,072
  u16*   bb_bf    = (u16*)(ws + 18759680);       // 4,194,304

  (void)hipMemsetAsync(flags, 0, 16384, stream);
  k_prep_w  <<<8192, 256, 0, stream>>>(W_ih, W_hh, Wf);
  k_prep_kf <<<4608, 256, 0, stream>>>(K_conv_f, Kf);
  k_prep_wcf2<<<512, 256, 0, stream>>>(W_conv_h, WcF2);
  k_prep_wp <<<256,  256, 0, stream>>>(W_fcp, WpF);
  k_hc      <<<256,  256, 0, stream>>>(z_vec, W_fc_hc, b_fc_hc, h_pack, c_ws);
  k_conv    <<<256,  256, 0, stream>>>(backbone, Kf, b_conv_f, x_em, bb_bf);
  k_rnn     <<<256,  256, 0, stream>>>(bb_bf, sketch, b_conv_h, W_att, W_ih, b_ih, b_hh,
                                       x_em, Wf, WcF2, WpF, b_fcp,
                                       h_pack, att_pack, c_ws, flags, (float*)d_out);
}